// Round 1
// baseline (178.777 us; speedup 1.0000x reference)
//
#include <hip/hip_runtime.h>

// ResidualVQ forward: out[n] = codebook[argmin_k(-2 x.c_k + ||c_k||^2)]
// (straight-through: out == quantized; SCALE_FACTOR == 1.0)

constexpr int D = 128;          // embedding dim (fixed by problem)
constexpr int ROWS = 64;        // rows per block (= lanes per wave)
constexpr int KSPLITS = 4;      // waves per block, each handles K/KSPLITS codes

// --- kernel 0: codebook squared norms into ws ---
__global__ __launch_bounds__(256) void cnorm_kernel(const float* __restrict__ cb,
                                                    float* __restrict__ cnorm, int K) {
    int k = blockIdx.x * blockDim.x + threadIdx.x;
    if (k >= K) return;
    const float4* c = (const float4*)(cb + (size_t)k * D);
    float s0 = 0.f, s1 = 0.f, s2 = 0.f, s3 = 0.f;
#pragma unroll
    for (int i = 0; i < D / 4; ++i) {
        float4 v = c[i];
        s0 = fmaf(v.x, v.x, s0);
        s1 = fmaf(v.y, v.y, s1);
        s2 = fmaf(v.z, v.z, s2);
        s3 = fmaf(v.w, v.w, s3);
    }
    cnorm[k] = (s0 + s1) + (s2 + s3);
}

// --- kernel 1: fused argmin + gather ---
// block = 256 threads = 4 waves. Wave w handles K-split w for the block's 64 rows.
// lane l <-> row l. k is wave-uniform -> codebook row loads become s_load (SGPR),
// leaving the VALU purely for v_fmac_f32 v,s,v.
__global__ __launch_bounds__(256) void vq_argmin_gather(const float* __restrict__ x,
                                                        const float* __restrict__ cb,
                                                        const float* __restrict__ cnorm,
                                                        float* __restrict__ out,
                                                        int N, int K) {
    const int lane = threadIdx.x & 63;
    const int wave = threadIdx.x >> 6;
    int row = blockIdx.x * ROWS + lane;
    if (row >= N) row = N - 1;  // safe clamp (N is a multiple of 64 in practice)

    // load this row of x into registers (fully unrolled -> stays in VGPRs)
    float xr[D];
    {
        const float4* xp = (const float4*)(x + (size_t)row * D);
#pragma unroll
        for (int i = 0; i < D / 4; ++i) {
            float4 v = xp[i];
            xr[4 * i + 0] = v.x;
            xr[4 * i + 1] = v.y;
            xr[4 * i + 2] = v.z;
            xr[4 * i + 3] = v.w;
        }
    }

    const int kper = K / KSPLITS;  // 256
    const int k0 = wave * kper;

    float best = 3.4e38f;
    int bidx = 0x7fffffff;

#pragma unroll 2
    for (int j = 0; j < kper; ++j) {
        // wave-uniform code index -> scalar (SGPR) loads of the codebook row
        const int k = __builtin_amdgcn_readfirstlane(k0 + j);
        const float* __restrict__ c = cb + (size_t)k * D;
        float d0 = 0.f, d1 = 0.f, d2 = 0.f, d3 = 0.f;
#pragma unroll
        for (int i = 0; i < D; i += 4) {
            d0 = fmaf(xr[i + 0], c[i + 0], d0);
            d1 = fmaf(xr[i + 1], c[i + 1], d1);
            d2 = fmaf(xr[i + 2], c[i + 2], d2);
            d3 = fmaf(xr[i + 3], c[i + 3], d3);
        }
        float dot = (d0 + d1) + (d2 + d3);
        float dist = cnorm[k] - 2.0f * dot;
        // strict < keeps the lowest index on ties (k ascending)
        if (dist < best) {
            best = dist;
            bidx = k;
        }
    }

    // cross-wave argmin reduction via LDS
    __shared__ float sdist[KSPLITS][ROWS];
    __shared__ int sidx[KSPLITS][ROWS];
    __shared__ int fidx[ROWS];
    sdist[wave][lane] = best;
    sidx[wave][lane] = bidx;
    __syncthreads();
    if (wave == 0) {
        float b = sdist[0][lane];
        int bi = sidx[0][lane];
#pragma unroll
        for (int w = 1; w < KSPLITS; ++w) {
            float dw = sdist[w][lane];
            int iw = sidx[w][lane];
            if (dw < b || (dw == b && iw < bi)) {
                b = dw;
                bi = iw;
            }
        }
        fidx[lane] = bi;
    }
    __syncthreads();

    // gather: 256 threads write 64 rows x 128 floats; thread t handles a
    // contiguous 32-float chunk -> coalesced float4 stores.
    const int r = threadIdx.x >> 2;
    const int ch = threadIdx.x & 3;
    int grow = blockIdx.x * ROWS + r;
    if (grow >= N) grow = N - 1;
    const int src = fidx[r];
    const float4* cs = (const float4*)(cb + (size_t)src * D + ch * 32);
    float4* od = (float4*)(out + (size_t)grow * D + ch * 32);
#pragma unroll
    for (int i = 0; i < 8; ++i) od[i] = cs[i];
}

extern "C" void kernel_launch(void* const* d_in, const int* in_sizes, int n_in,
                              void* d_out, int out_size, void* d_ws, size_t ws_size,
                              hipStream_t stream) {
    const float* x = (const float*)d_in[0];
    const float* cb = (const float*)d_in[1];
    float* out = (float*)d_out;
    const int N = in_sizes[0] / D;
    const int K = in_sizes[1] / D;
    float* cnorm = (float*)d_ws;  // K floats (4 KB)

    hipLaunchKernelGGL(cnorm_kernel, dim3((K + 255) / 256), dim3(256), 0, stream,
                       cb, cnorm, K);
    hipLaunchKernelGGL(vq_argmin_gather, dim3((N + ROWS - 1) / ROWS), dim3(256), 0,
                       stream, x, cb, cnorm, out, N, K);
}